// Round 1
// baseline (445.676 us; speedup 1.0000x reference)
//
#include <hip/hip_runtime.h>
#include <hip/hip_bf16.h>

#define IN_DIM   128
#define HIDDEN   256
#define OUT_DIM  128
#define N_NODES  100000
#define N_EDGES  500000
#define N_ROWS   (2 * N_EDGES)   // 2 MC x edges = 1,000,000

typedef __bf16 bf16x8 __attribute__((ext_vector_type(8)));
typedef float  f32x4  __attribute__((ext_vector_type(4)));

// ws layout (bytes):
//   [0, 131072)        W1s: 256 rows(n) x 512 B (K=256 bf16, XOR-swizzled within row)
//   [131072, 196608)   W2s: 128 rows(n) x 512 B
#define W1S_OFF 0
#define W2S_OFF 131072

// Pre-swizzle rule (involution, 16B granules): stored[n][kb] = W^T[n][kb ^ ((n&7)<<4)]
// so that a LINEAR global_load_lds copy + swizzled ds_read_b128 yields W^T[n][k].
__global__ void prep_weights(const float* __restrict__ W1,
                             const float* __restrict__ W2,
                             unsigned char* __restrict__ ws) {
  int t = blockIdx.x * 256 + threadIdx.x;
  if (t < HIDDEN * HIDDEN) {           // W1: [k=256][n=256] row-major input
    int n = t & 255, k = t >> 8;
    __bf16 b = (__bf16)W1[k * HIDDEN + n];
    int byte = W1S_OFF + n * 512 + ((k * 2) ^ ((n & 7) << 4));
    *reinterpret_cast<__bf16*>(ws + byte) = b;
  } else {
    int t2 = t - HIDDEN * HIDDEN;
    if (t2 < HIDDEN * OUT_DIM) {       // W2: [k=256][n=128]
      int n = t2 & 127, k = t2 >> 7;
      __bf16 b = (__bf16)W2[k * OUT_DIM + n];
      int byte = W2S_OFF + n * 512 + ((k * 2) ^ ((n & 7) << 4));
      *reinterpret_cast<__bf16*>(ws + byte) = b;
    }
  }
}

__global__ __launch_bounds__(256)
void edge_mlp(const int* __restrict__ eidx,
              const float* __restrict__ x,
              const float* __restrict__ b1,
              const float* __restrict__ b2,
              const unsigned char* __restrict__ ws,
              float* __restrict__ out) {
  __shared__ __align__(16) unsigned char wbuf[32768];  // weight chunk [64n][512B]
  __shared__ __align__(16) unsigned char hbuf[32768];  // h [64 rows][512B] swizzled

  const int tid  = threadIdx.x;
  const int wv   = tid >> 6;           // wave 0..3
  const int lane = tid & 63;
  const int l15  = lane & 15;
  const int lk   = lane >> 4;          // 0..3 (k-group)

  const long base = (long)blockIdx.x * 64;
  const long gr   = base + wv * 16 + l15;        // this lane's A-row (global)
  const int  mc   = (gr >= N_EDGES) ? 1 : 0;
  const int  e    = (int)(gr - (long)mc * N_EDGES);
  const int  sn   = eidx[e];
  const int  dn   = eidx[N_EDGES + e];
  const float* xs = x + ((long)mc * N_NODES + sn) * IN_DIM;
  const float* xd = x + ((long)mc * N_NODES + dn) * IN_DIM;

  // ---- gather layer-1 A fragments (K=256 = concat(src,dst)), fp32 -> bf16 ----
  // A-frag layout (16x16x32): lane holds row=l&15, k = (l>>4)*8 + j (8 consecutive)
  bf16x8 a1[8];
#pragma unroll
  for (int kt = 0; kt < 8; ++kt) {
    int k = kt * 32 + lk * 8;
    const float* p = (k < IN_DIM) ? (xs + k) : (xd + (k - IN_DIM));
    float4 f0 = *reinterpret_cast<const float4*>(p);
    float4 f1 = *reinterpret_cast<const float4*>(p + 4);
    bf16x8 a;
    a[0] = (__bf16)f0.x; a[1] = (__bf16)f0.y; a[2] = (__bf16)f0.z; a[3] = (__bf16)f0.w;
    a[4] = (__bf16)f1.x; a[5] = (__bf16)f1.y; a[6] = (__bf16)f1.z; a[7] = (__bf16)f1.w;
    a1[kt] = a;
  }

  // ---- layer 1: h = relu(A @ W1 + b1), 4 N-chunks of 64 cols ----
#pragma unroll 1
  for (int c = 0; c < 4; ++c) {
    __syncthreads();   // protect wbuf from previous chunk's readers
    {
      const unsigned char* gsrc = ws + W1S_OFF + c * 32768;
#pragma unroll
      for (int it = 0; it < 8; ++it) {
        int off = wv * 8192 + it * 1024;
        __builtin_amdgcn_global_load_lds(
            (const __attribute__((address_space(1))) unsigned int*)(gsrc + off + lane * 16),
            (__attribute__((address_space(3))) unsigned int*)(wbuf + off),
            16, 0, 0);
      }
    }
    __syncthreads();   // vmcnt(0) drained by barrier

    f32x4 acc[4];
#pragma unroll
    for (int nt = 0; nt < 4; ++nt) acc[nt] = (f32x4){0.f, 0.f, 0.f, 0.f};
#pragma unroll
    for (int kt = 0; kt < 8; ++kt) {
#pragma unroll
      for (int nt = 0; nt < 4; ++nt) {
        int n  = nt * 16 + l15;
        int kb = kt * 64 + lk * 16;
        const bf16x8 b = *reinterpret_cast<const bf16x8*>(
            wbuf + n * 512 + (kb ^ ((n & 7) << 4)));
        acc[nt] = __builtin_amdgcn_mfma_f32_16x16x32_bf16(a1[kt], b, acc[nt], 0, 0, 0);
      }
    }
    // bias + relu + h tile -> LDS (bf16, swizzled). C/D: col=l&15, row=(l>>4)*4+r
#pragma unroll
    for (int nt = 0; nt < 4; ++nt) {
      int col  = c * 64 + nt * 16 + l15;
      float bv = b1[col];
#pragma unroll
      for (int r = 0; r < 4; ++r) {
        float v = fmaxf(acc[nt][r] + bv, 0.f);
        int row = wv * 16 + lk * 4 + r;
        int byte = row * 512 + ((col * 2) ^ ((row & 7) << 4));
        *reinterpret_cast<__bf16*>(hbuf + byte) = (__bf16)v;
      }
    }
  }

  // ---- layer-2 A fragments from hbuf (wave reads only its own 16 rows) ----
  bf16x8 a2[8];
#pragma unroll
  for (int kt = 0; kt < 8; ++kt) {
    int row = wv * 16 + l15;
    int kb  = kt * 64 + lk * 16;
    a2[kt] = *reinterpret_cast<const bf16x8*>(
        hbuf + row * 512 + (kb ^ ((row & 7) << 4)));
  }

  // ---- layer 2: out = h @ W2 + b2, 2 N-chunks of 64 cols ----
#pragma unroll 1
  for (int c2 = 0; c2 < 2; ++c2) {
    __syncthreads();   // protect wbuf (layer-1 chunk-3 readers / previous chunk)
    {
      const unsigned char* gsrc = ws + W2S_OFF + c2 * 32768;
#pragma unroll
      for (int it = 0; it < 8; ++it) {
        int off = wv * 8192 + it * 1024;
        __builtin_amdgcn_global_load_lds(
            (const __attribute__((address_space(1))) unsigned int*)(gsrc + off + lane * 16),
            (__attribute__((address_space(3))) unsigned int*)(wbuf + off),
            16, 0, 0);
      }
    }
    __syncthreads();

    f32x4 acc[4];
#pragma unroll
    for (int nt = 0; nt < 4; ++nt) acc[nt] = (f32x4){0.f, 0.f, 0.f, 0.f};
#pragma unroll
    for (int kt = 0; kt < 8; ++kt) {
#pragma unroll
      for (int nt = 0; nt < 4; ++nt) {
        int n  = nt * 16 + l15;
        int kb = kt * 64 + lk * 16;
        const bf16x8 b = *reinterpret_cast<const bf16x8*>(
            wbuf + n * 512 + (kb ^ ((n & 7) << 4)));
        acc[nt] = __builtin_amdgcn_mfma_f32_16x16x32_bf16(a2[kt], b, acc[nt], 0, 0, 0);
      }
    }
#pragma unroll
    for (int nt = 0; nt < 4; ++nt) {
      int col  = c2 * 64 + nt * 16 + l15;
      float bv = b2[col];
#pragma unroll
      for (int r = 0; r < 4; ++r) {
        long grr = base + wv * 16 + lk * 4 + r;
        out[grr * OUT_DIM + col] = acc[nt][r] + bv;
      }
    }
  }
}

extern "C" void kernel_launch(void* const* d_in, const int* in_sizes, int n_in,
                              void* d_out, int out_size, void* d_ws, size_t ws_size,
                              hipStream_t stream) {
  const int*   eidx = (const int*)d_in[0];
  const float* x    = (const float*)d_in[1];
  const float* W1   = (const float*)d_in[2];
  const float* b1   = (const float*)d_in[3];
  const float* W2   = (const float*)d_in[4];
  const float* b2   = (const float*)d_in[5];
  float* out = (float*)d_out;
  unsigned char* ws = (unsigned char*)d_ws;

  // weights -> bf16, transposed + pre-swizzled into ws (196608 B)
  prep_weights<<<(HIDDEN * HIDDEN + HIDDEN * OUT_DIM) / 256, 256, 0, stream>>>(
      (const float*)d_in[2], (const float*)d_in[4], ws);

  // 64 rows per block
  edge_mlp<<<N_ROWS / 64, 256, 0, stream>>>(eidx, x, b1, b2, ws, out);
  (void)in_sizes; (void)n_in; (void)out_size; (void)ws_size; (void)W1; (void)W2;
}

// Round 2
// 386.316 us; speedup vs baseline: 1.1537x; 1.1537x over previous
//
#include <hip/hip_runtime.h>
#include <hip/hip_bf16.h>

#define IN_DIM   128
#define HIDDEN   256
#define OUT_DIM  128
#define N_NODES  100000
#define N_EDGES  500000
#define N_ROWS   (2 * N_EDGES)   // 1,000,000 rows (2 MC x edges)

typedef __bf16 bf16x8 __attribute__((ext_vector_type(8)));
typedef float  f32x4  __attribute__((ext_vector_type(4)));

// ws layout: 24 chunks x 8192 B, each chunk = 16 output-cols x 512 B (K=256 bf16,
// XOR-swizzled within row by ((n&7)<<4)).  Chunks 0..15 = W1^T, 16..23 = W2^T.
#define W1S_OFF 0
#define W2S_OFF 131072

__global__ void prep_weights(const float* __restrict__ W1,
                             const float* __restrict__ W2,
                             unsigned char* __restrict__ ws) {
  int t = blockIdx.x * 256 + threadIdx.x;
  if (t < HIDDEN * HIDDEN) {           // W1: [k=256][n=256] row-major input
    int n = t & 255, k = t >> 8;
    __bf16 b = (__bf16)W1[k * HIDDEN + n];
    int byte = W1S_OFF + n * 512 + ((k * 2) ^ ((n & 7) << 4));
    *reinterpret_cast<__bf16*>(ws + byte) = b;
  } else {
    int t2 = t - HIDDEN * HIDDEN;
    if (t2 < HIDDEN * OUT_DIM) {       // W2: [k=256][n=128]
      int n = t2 & 127, k = t2 >> 7;
      __bf16 b = (__bf16)W2[k * OUT_DIM + n];
      int byte = W2S_OFF + n * 512 + ((k * 2) ^ ((n & 7) << 4));
      *reinterpret_cast<__bf16*>(ws + byte) = b;
    }
  }
}

static __device__ __forceinline__ unsigned pack_bf16(float a, float b) {
  __bf16 x = (__bf16)a, y = (__bf16)b;
  unsigned short ux = __builtin_bit_cast(unsigned short, x);
  unsigned short uy = __builtin_bit_cast(unsigned short, y);
  return (unsigned)ux | ((unsigned)uy << 16);
}

__global__ __launch_bounds__(256, 4)
void edge_mlp(const int* __restrict__ eidx,
              const float* __restrict__ x,
              const float* __restrict__ b1,
              const float* __restrict__ b2,
              const unsigned char* __restrict__ ws,
              float* __restrict__ out) {
  __shared__ __align__(16) unsigned char wbuf[2][8192];

  const int tid  = threadIdx.x;
  const int wv   = tid >> 6;
  const int lane = tid & 63;
  const int l15  = lane & 15;
  const int lk   = lane >> 4;

  const long base = (long)blockIdx.x * 64;
  const long gr   = base + wv * 16 + l15;   // this lane's gather row (exact grid)
  const int  mc   = (gr >= N_EDGES) ? 1 : 0;
  const int  e    = (int)(gr - (long)mc * N_EDGES);
  const int  sn   = eidx[e];
  const int  dn   = eidx[N_EDGES + e];
  const float* xs = x + ((long)mc * N_NODES + sn) * IN_DIM;
  const float* xd = x + ((long)mc * N_NODES + dn) * IN_DIM;

  // ---- gather x fragments (B-operand of swapped layer 1): lane holds
  //      edge = l15, k = lk*8 + kt*32 (8 consecutive), fp32 -> bf16 ----
  bf16x8 a1[8];
#pragma unroll
  for (int kt = 0; kt < 8; ++kt) {
    int k = kt * 32 + lk * 8;
    const float* p = (k < IN_DIM) ? (xs + k) : (xd + (k - IN_DIM));
    float4 f0 = *reinterpret_cast<const float4*>(p);
    float4 f1 = *reinterpret_cast<const float4*>(p + 4);
    bf16x8 a;
    a[0] = (__bf16)f0.x; a[1] = (__bf16)f0.y; a[2] = (__bf16)f0.z; a[3] = (__bf16)f0.w;
    a[4] = (__bf16)f1.x; a[5] = (__bf16)f1.y; a[6] = (__bf16)f1.z; a[7] = (__bf16)f1.w;
    a1[kt] = a;
  }

#define STAGE(t, buf)                                                          \
  do {                                                                         \
    const unsigned char* g_ = ws + (t) * 8192;                                 \
    __builtin_amdgcn_global_load_lds(                                          \
        (const __attribute__((address_space(1))) unsigned int*)(g_ + tid * 16),\
        (__attribute__((address_space(3))) unsigned int*)(&wbuf[buf][tid * 16]),\
        16, 0, 0);                                                             \
    __builtin_amdgcn_global_load_lds(                                          \
        (const __attribute__((address_space(1))) unsigned int*)(g_ + 4096 + tid * 16), \
        (__attribute__((address_space(3))) unsigned int*)(&wbuf[buf][4096 + tid * 16]), \
        16, 0, 0);                                                             \
  } while (0)

  STAGE(0, 0);
  __syncthreads();

  const int swz  = (l15 & 7) << 4;
  const int rowb = l15 * 512;
  const int s0   = (lk & 1) * 32 + l15;  // shuffle source lanes
  const int s1   = s0 + 16;
  const bool hi  = (lk >= 2);

  bf16x8 a2[8];
  unsigned pe0 = 0, pe1 = 0;

  // ---- layer 1 (swapped): per 16-hcol chunk c, D[hcol][edge] += W1^T x ----
#pragma unroll
  for (int c = 0; c < 16; ++c) {
    STAGE(c + 1, (c + 1) & 1);          // prefetch next chunk (c+1 <= 16)
    f32x4 acc = (f32x4){0.f, 0.f, 0.f, 0.f};
#pragma unroll
    for (int kt = 0; kt < 8; ++kt) {
      bf16x8 wf = *reinterpret_cast<const bf16x8*>(
          &wbuf[c & 1][rowb + ((kt * 64 + lk * 16) ^ swz)]);
      acc = __builtin_amdgcn_mfma_f32_16x16x32_bf16(wf, a1[kt], acc, 0, 0, 0);
    }
    // bias + relu: lane holds hcol = c*16 + lk*4 + r, edge = l15
    float4 bv = *reinterpret_cast<const float4*>(b1 + c * 16 + lk * 4);
    unsigned p0 = pack_bf16(fmaxf(acc[0] + bv.x, 0.f), fmaxf(acc[1] + bv.y, 0.f));
    unsigned p1 = pack_bf16(fmaxf(acc[2] + bv.z, 0.f), fmaxf(acc[3] + bv.w, 0.f));
    if ((c & 1) == 0) {
      pe0 = p0; pe1 = p1;               // even chunk: hold for the pair-shuffle
    } else {
      // build a2[c>>1]: lane (l15,lk) needs h[edge=l15][kt2*32+lk*8+j], j=0..7
      unsigned A0 = (unsigned)__shfl((int)pe0, s0), A1 = (unsigned)__shfl((int)pe1, s0);
      unsigned A2 = (unsigned)__shfl((int)pe0, s1), A3 = (unsigned)__shfl((int)pe1, s1);
      unsigned B0 = (unsigned)__shfl((int)p0, s0),  B1 = (unsigned)__shfl((int)p1, s0);
      unsigned B2 = (unsigned)__shfl((int)p0, s1),  B3 = (unsigned)__shfl((int)p1, s1);
      uint4 w;
      w.x = hi ? B0 : A0; w.y = hi ? B1 : A1;
      w.z = hi ? B2 : A2; w.w = hi ? B3 : A3;
      a2[c >> 1] = __builtin_bit_cast(bf16x8, w);
    }
    __syncthreads();                     // drains STAGE(c+1) + protects wbuf
  }

  // ---- layer 2 (standard): out[edge][ocol] = h @ W2 + b2 ----
#pragma unroll
  for (int c2 = 0; c2 < 8; ++c2) {
    const int t = 16 + c2;
    if (t + 1 < 24) STAGE(t + 1, (t + 1) & 1);
    f32x4 acc = (f32x4){0.f, 0.f, 0.f, 0.f};
#pragma unroll
    for (int kt = 0; kt < 8; ++kt) {
      bf16x8 bf = *reinterpret_cast<const bf16x8*>(
          &wbuf[t & 1][rowb + ((kt * 64 + lk * 16) ^ swz)]);
      acc = __builtin_amdgcn_mfma_f32_16x16x32_bf16(a2[kt], bf, acc, 0, 0, 0);
    }
    // C layout: col = ocol = c2*16 + l15, row = edge_local = lk*4 + r
    float bv2 = b2[c2 * 16 + l15];
    const long r0 = base + wv * 16 + lk * 4;
#pragma unroll
    for (int r = 0; r < 4; ++r)
      out[(r0 + r) * OUT_DIM + c2 * 16 + l15] = acc[r] + bv2;
    if (c2 < 7) __syncthreads();
  }
#undef STAGE
}

extern "C" void kernel_launch(void* const* d_in, const int* in_sizes, int n_in,
                              void* d_out, int out_size, void* d_ws, size_t ws_size,
                              hipStream_t stream) {
  const int*   eidx = (const int*)d_in[0];
  const float* x    = (const float*)d_in[1];
  const float* b1   = (const float*)d_in[3];
  const float* b2   = (const float*)d_in[5];
  float* out = (float*)d_out;
  unsigned char* ws = (unsigned char*)d_ws;

  prep_weights<<<(HIDDEN * HIDDEN + HIDDEN * OUT_DIM) / 256, 256, 0, stream>>>(
      (const float*)d_in[2], (const float*)d_in[4], ws);

  edge_mlp<<<N_ROWS / 64, 256, 0, stream>>>(eidx, x, b1, b2, ws, out);
  (void)in_sizes; (void)n_in; (void)out_size; (void)ws_size;
}

// Round 3
// 359.446 us; speedup vs baseline: 1.2399x; 1.0748x over previous
//
#include <hip/hip_runtime.h>
#include <hip/hip_bf16.h>

#define IN_DIM   128
#define HIDDEN   256
#define OUT_DIM  128
#define N_NODES  100000
#define N_EDGES  500000
#define N_ROWS   (2 * N_EDGES)   // 1,000,000 rows (2 MC x edges)

typedef __bf16 bf16x8  __attribute__((ext_vector_type(8)));
typedef float  f32x16  __attribute__((ext_vector_type(16)));

// ws: 12 chunks x 16384 B. Chunk = 32 output-cols (n) x 512 B (K=256 bf16,
// XOR-swizzled by ((n&7)<<4) in 16B granules). Chunks 0..7 = W1^T, 8..11 = W2^T.
#define W1S_OFF 0
#define W2S_OFF 131072

__global__ void prep_weights(const float* __restrict__ W1,
                             const float* __restrict__ W2,
                             unsigned char* __restrict__ ws) {
  int t = blockIdx.x * 256 + threadIdx.x;
  if (t < HIDDEN * HIDDEN) {           // W1: [k=256][n=256] row-major input
    int n = t & 255, k = t >> 8;
    __bf16 b = (__bf16)W1[k * HIDDEN + n];
    int byte = W1S_OFF + n * 512 + ((k * 2) ^ ((n & 7) << 4));
    *reinterpret_cast<__bf16*>(ws + byte) = b;
  } else {
    int t2 = t - HIDDEN * HIDDEN;
    if (t2 < HIDDEN * OUT_DIM) {       // W2: [k=256][n=128]
      int n = t2 & 127, k = t2 >> 7;
      __bf16 b = (__bf16)W2[k * OUT_DIM + n];
      int byte = W2S_OFF + n * 512 + ((k * 2) ^ ((n & 7) << 4));
      *reinterpret_cast<__bf16*>(ws + byte) = b;
    }
  }
}

static __device__ __forceinline__ unsigned pack_bf16(float a, float b) {
  __bf16 x = (__bf16)a, y = (__bf16)b;
  unsigned short ux = __builtin_bit_cast(unsigned short, x);
  unsigned short uy = __builtin_bit_cast(unsigned short, y);
  return (unsigned)ux | ((unsigned)uy << 16);
}

__global__ __launch_bounds__(128)
void edge_mlp(const int* __restrict__ eidx,
              const float* __restrict__ x,
              const float* __restrict__ b1,
              const float* __restrict__ b2,
              const unsigned char* __restrict__ ws,
              float* __restrict__ out) {
  __shared__ __align__(16) unsigned char wbuf[2][16384];

  const int tid  = threadIdx.x;
  const int wv   = tid >> 6;           // wave 0..1
  const int lane = tid & 63;
  const int el   = lane & 31;          // edge within wave tile
  const int hi   = lane >> 5;          // k half

  const long base = (long)blockIdx.x * 64;
  const long gr   = base + wv * 32 + el;
  const int  mc   = (gr >= N_EDGES) ? 1 : 0;
  const int  e    = (int)(gr - (long)mc * N_EDGES);
  const int  sn   = eidx[e];
  const int  dn   = eidx[N_EDGES + e];
  const float* xs = x + ((long)mc * N_NODES + sn) * IN_DIM;
  const float* xd = x + ((long)mc * N_NODES + dn) * IN_DIM;

  // ---- x fragments (B of swapped L1, 32x32x16): lane holds edge=el,
  //      k = s*16 + hi*8 + j (8 consecutive) ----
  bf16x8 a1[16];
#pragma unroll
  for (int s = 0; s < 16; ++s) {
    int k0 = s * 16 + hi * 8;
    const float* p = (s < 8) ? (xs + k0) : (xd + (k0 - IN_DIM));
    float4 f0 = *reinterpret_cast<const float4*>(p);
    float4 f1 = *reinterpret_cast<const float4*>(p + 4);
    bf16x8 a;
    a[0] = (__bf16)f0.x; a[1] = (__bf16)f0.y; a[2] = (__bf16)f0.z; a[3] = (__bf16)f0.w;
    a[4] = (__bf16)f1.x; a[5] = (__bf16)f1.y; a[6] = (__bf16)f1.z; a[7] = (__bf16)f1.w;
    a1[s] = a;
  }

#define STAGE(t, b)                                                            \
  do {                                                                         \
    const unsigned char* g_ = ws + (t) * 16384;                                \
    _Pragma("unroll")                                                          \
    for (int i_ = 0; i_ < 8; ++i_) {                                           \
      __builtin_amdgcn_global_load_lds(                                        \
          (const __attribute__((address_space(1))) unsigned int*)(g_ + i_ * 2048 + tid * 16), \
          (__attribute__((address_space(3))) unsigned int*)(&wbuf[b][i_ * 2048 + tid * 16]),  \
          16, 0, 0);                                                           \
    }                                                                          \
  } while (0)

  STAGE(0, 0);
  __syncthreads();

  const int rowb = el * 512;
  const int swz  = (el & 7) << 4;

  bf16x8 a2[16];

  // ---- layer 1 (swapped): per 32-hcol chunk cc, D[hcol][edge] = W1^T x ----
#pragma unroll
  for (int cc = 0; cc < 8; ++cc) {
    STAGE(cc + 1, (cc + 1) & 1);        // chunks 1..8
    f32x16 acc = {};
#pragma unroll
    for (int ks = 0; ks < 16; ++ks) {
      bf16x8 wf = *reinterpret_cast<const bf16x8*>(
          &wbuf[cc & 1][rowb + ((ks * 32 + hi * 16) ^ swz)]);
      acc = __builtin_amdgcn_mfma_f32_32x32x16_bf16(wf, a1[ks], acc, 0, 0, 0);
    }
    // C: col=edge=el, row m=(reg&3)+8*(reg>>2)+4*hi; hcol = cc*32 + m
    float4 bv0 = *reinterpret_cast<const float4*>(b1 + cc * 32 + hi * 4);
    float4 bv1 = *reinterpret_cast<const float4*>(b1 + cc * 32 + 8 + hi * 4);
    float4 bv2 = *reinterpret_cast<const float4*>(b1 + cc * 32 + 16 + hi * 4);
    float4 bv3 = *reinterpret_cast<const float4*>(b1 + cc * 32 + 24 + hi * 4);
    unsigned w0 = pack_bf16(fmaxf(acc[0] + bv0.x, 0.f),  fmaxf(acc[1] + bv0.y, 0.f));
    unsigned w1 = pack_bf16(fmaxf(acc[2] + bv0.z, 0.f),  fmaxf(acc[3] + bv0.w, 0.f));
    unsigned w2 = pack_bf16(fmaxf(acc[4] + bv1.x, 0.f),  fmaxf(acc[5] + bv1.y, 0.f));
    unsigned w3 = pack_bf16(fmaxf(acc[6] + bv1.z, 0.f),  fmaxf(acc[7] + bv1.w, 0.f));
    unsigned w4 = pack_bf16(fmaxf(acc[8] + bv2.x, 0.f),  fmaxf(acc[9] + bv2.y, 0.f));
    unsigned w5 = pack_bf16(fmaxf(acc[10] + bv2.z, 0.f), fmaxf(acc[11] + bv2.w, 0.f));
    unsigned w6 = pack_bf16(fmaxf(acc[12] + bv3.x, 0.f), fmaxf(acc[13] + bv3.y, 0.f));
    unsigned w7 = pack_bf16(fmaxf(acc[14] + bv3.z, 0.f), fmaxf(acc[15] + bv3.w, 0.f));
    // half-wave exchange: vdst' = (a.row0, b.row0); vsrc' = (a.row1, b.row1)
    asm("v_permlane32_swap_b32 %0, %1" : "+v"(w0), "+v"(w2));
    asm("v_permlane32_swap_b32 %0, %1" : "+v"(w1), "+v"(w3));
    asm("v_permlane32_swap_b32 %0, %1" : "+v"(w4), "+v"(w6));
    asm("v_permlane32_swap_b32 %0, %1" : "+v"(w5), "+v"(w7));
    uint4 fe; fe.x = w0; fe.y = w1; fe.z = w2; fe.w = w3;
    uint4 fo; fo.x = w4; fo.y = w5; fo.z = w6; fo.w = w7;
    a2[2 * cc]     = __builtin_bit_cast(bf16x8, fe);
    a2[2 * cc + 1] = __builtin_bit_cast(bf16x8, fo);
    __syncthreads();
  }

  // ---- layer 2 (standard): out[edge][ocol] = h @ W2 + b2 ----
#pragma unroll
  for (int oc = 0; oc < 4; ++oc) {
    const int t = 8 + oc;
    if (t + 1 < 12) STAGE(t + 1, (t + 1) & 1);
    f32x16 acc = {};
#pragma unroll
    for (int kk = 0; kk < 16; ++kk) {
      bf16x8 wf = *reinterpret_cast<const bf16x8*>(
          &wbuf[t & 1][rowb + ((kk * 32 + hi * 16) ^ swz)]);
      acc = __builtin_amdgcn_mfma_f32_32x32x16_bf16(a2[kk], wf, acc, 0, 0, 0);
    }
    float bvo = b2[oc * 32 + el];
    const long r0 = base + wv * 32;
#pragma unroll
    for (int reg = 0; reg < 16; ++reg) {
      int m = (reg & 3) + 8 * (reg >> 2) + 4 * hi;
      out[(r0 + m) * OUT_DIM + oc * 32 + el] = acc[reg] + bvo;
    }
    if (oc < 3) __syncthreads();
  }
#undef STAGE
}

extern "C" void kernel_launch(void* const* d_in, const int* in_sizes, int n_in,
                              void* d_out, int out_size, void* d_ws, size_t ws_size,
                              hipStream_t stream) {
  const int*   eidx = (const int*)d_in[0];
  const float* x    = (const float*)d_in[1];
  const float* b1   = (const float*)d_in[3];
  const float* b2   = (const float*)d_in[5];
  float* out = (float*)d_out;
  unsigned char* ws = (unsigned char*)d_ws;

  prep_weights<<<(HIDDEN * HIDDEN + HIDDEN * OUT_DIM) / 256, 256, 0, stream>>>(
      (const float*)d_in[2], (const float*)d_in[4], ws);

  edge_mlp<<<N_ROWS / 64, 128, 0, stream>>>(eidx, x, b1, b2, ws, out);
  (void)in_sizes; (void)n_in; (void)out_size; (void)ws_size;
}